// Round 10
// baseline (277.129 us; speedup 1.0000x reference)
//
#include <hip/hip_runtime.h>
#include <hip/hip_fp16.h>

#define TT 256
#define PP 88
#define CC 128
#define NN (TT * PP)          // 22528 positions
#define NPAD (NN + 32)
#define HEADS 4
#define HD 32
#define WIN 25
#define RPBW 49
#define RPBSZ (RPBW * RPBW)   // 2401
#define SCALE 0.17677669529663687f   // 1/sqrt(32)
#define LOG2E 1.4426950408889634f
#define QSC (SCALE * LOG2E)          // fold exp->exp2 into Q path

#if __has_builtin(__builtin_amdgcn_exp2f)
#define EXP2(x) __builtin_amdgcn_exp2f(x)
#else
#define EXP2(x) exp2f(x)
#endif

typedef _Float16 f16;
typedef f16 f16x8 __attribute__((ext_vector_type(8)));
typedef f16 f16x8u __attribute__((ext_vector_type(8), aligned(4)));
typedef float f32x4 __attribute__((ext_vector_type(4)));
typedef float f32x4u __attribute__((ext_vector_type(4), aligned(4)));
typedef __fp16 hf16x2 __attribute__((ext_vector_type(2)));
union PkU { hf16x2 h; unsigned u; };

// ---------- prep: light repack only (no serial GEMM loop except tiny b2s) ----------
__global__ void prep(const float* __restrict__ lw, const float* __restrict__ qw,
                     const float* __restrict__ pw, const float* __restrict__ qb,
                     const float* __restrict__ pb, const float* __restrict__ rpb,
                     f16* __restrict__ lwh, f16* __restrict__ qwh, f16* __restrict__ pwh,
                     f16* __restrict__ pwt, float* __restrict__ qbs, float* __restrict__ b2s,
                     float* __restrict__ rpbp) {
    int idx = blockIdx.x * 256 + threadIdx.x;     // 192*256 = 49152
    if (idx < 128 * 160) {                        // fusion W: [128][131] -> [128][160] pad
        int r = idx / 160, c = idx - r * 160;
        lwh[idx] = (f16)(c < 131 ? lw[r * 131 + c] : 0.f);
    }
    if (idx < 384 * 128) {                        // qkv W, Q rows scaled by QSC
        float v = qw[idx];
        if (idx < 128 * 128) v *= QSC;
        qwh[idx] = (f16)v;
    }
    if (idx < 128 * 128) {
        pwh[idx] = (f16)pw[idx];                  // [out][in]
        int k = idx >> 7, j = idx & 127;
        pwt[idx] = (f16)pw[j * 128 + k];          // [in k][out j] transposed
    }
    if (idx < 384) {
        qbs[idx] = qb[idx] * (idx < 128 ? QSC : 1.f);
        float b = qb[idx];
        for (int j = 0; j < 128; j++) b += qw[idx * 128 + j] * pb[j];
        b2s[idx] = b * (idx < 128 ? QSC : 1.f);
    }
    if (idx < 10240) rpbp[idx] = (idx < 4 * RPBSZ) ? rpb[idx] * LOG2E : 0.f;
}

// ---------- w2h = qwh @ pwh (384x128, K=128) via MFMA; grid (2,6), no LDS ----------
// A = pwt (rows = k, contig j), B = qwh (rows = i, contig j). D[m=k][n=i].
__global__ __launch_bounds__(256) void wcomb_mfma(
    const f16* __restrict__ pwt, const f16* __restrict__ qwh, f16* __restrict__ w2h)
{
    const int m0 = blockIdx.x * 64;   // k
    const int n0 = blockIdx.y * 64;   // i
    const int tid = threadIdx.x;
    const int w = tid >> 6, lane = tid & 63, quad = lane >> 4, nn = lane & 15;

    f16x8 af[4];
    #pragma unroll
    for (int ks = 0; ks < 4; ks++)
        af[ks] = *(const f16x8*)&pwt[(size_t)(m0 + w * 16 + nn) * 128 + ks * 32 + quad * 8];

    f32x4 acc[4] = {};
    #pragma unroll
    for (int nt = 0; nt < 4; nt++)
        #pragma unroll
        for (int ks = 0; ks < 4; ks++) {
            f16x8 bf = *(const f16x8*)&qwh[(size_t)(n0 + nt * 16 + nn) * 128 + ks * 32 + quad * 8];
            acc[nt] = __builtin_amdgcn_mfma_f32_16x16x32_f16(af[ks], bf, acc[nt], 0, 0, 0);
        }

    #pragma unroll
    for (int nt = 0; nt < 4; nt++) {
        int i = n0 + nt * 16 + nn;
        int k = m0 + w * 16 + quad * 4;
        PkU p0, p1;
        p0.h = __builtin_amdgcn_cvt_pkrtz(acc[nt][0], acc[nt][1]);
        p1.h = __builtin_amdgcn_cvt_pkrtz(acc[nt][2], acc[nt][3]);
        *(uint2*)&w2h[(size_t)i * 128 + k] = make_uint2(p0.u, p1.u);
    }
}

// ---------- fusion GEMM: yh = relu(cat @ lwh^T + lb); grid (352, 2) ----------
__global__ __launch_bounds__(256) void fusion_gemm(
    const float* __restrict__ x, const float* __restrict__ cond, const float* __restrict__ mask,
    const f16* __restrict__ lwh, const float* __restrict__ lb, f16* __restrict__ yh)
{
    __shared__ __align__(16) f16 Alds[64 * 168];
    const int m0 = blockIdx.x * 64, n0 = blockIdx.y * 64;
    const int tid = threadIdx.x;
    const int w = tid >> 6, lane = tid & 63, quad = lane >> 4, nn = lane & 15;

    {   // stage cat rows (f16)
        int r = tid >> 2, cpart = tid & 3;
        size_t pos = m0 + r;
        *(uint4*)&Alds[r * 168 + 128 + cpart * 8] = make_uint4(0, 0, 0, 0);
        const float* xr = x + pos * 128 + cpart * 32;
        #pragma unroll
        for (int t = 0; t < 4; t++) {
            float4 a = *(const float4*)(xr + t * 8);
            float4 b = *(const float4*)(xr + t * 8 + 4);
            PkU p0, p1, p2, p3;
            p0.h = __builtin_amdgcn_cvt_pkrtz(a.x, a.y);
            p1.h = __builtin_amdgcn_cvt_pkrtz(a.z, a.w);
            p2.h = __builtin_amdgcn_cvt_pkrtz(b.x, b.y);
            p3.h = __builtin_amdgcn_cvt_pkrtz(b.z, b.w);
            *(uint4*)&Alds[r * 168 + cpart * 32 + t * 8] = make_uint4(p0.u, p1.u, p2.u, p3.u);
        }
        if (cpart == 0) {
            Alds[r * 168 + 128] = (f16)cond[pos * 2];
            Alds[r * 168 + 129] = (f16)cond[pos * 2 + 1];
            Alds[r * 168 + 130] = (f16)mask[pos];
        }
    }
    __syncthreads();

    const int oc = n0 + w * 16 + nn;
    f16x8 af[5];
    #pragma unroll
    for (int ks = 0; ks < 5; ks++)
        af[ks] = *(const f16x8*)&lwh[(size_t)oc * 160 + ks * 32 + quad * 8];
    f32x4 acc[4] = {};
    #pragma unroll
    for (int ks = 0; ks < 5; ks++)
        #pragma unroll
        for (int nt = 0; nt < 4; nt++) {
            f16x8 bf = *(const f16x8*)&Alds[(nt * 16 + nn) * 168 + ks * 32 + quad * 8];
            acc[nt] = __builtin_amdgcn_mfma_f32_16x16x32_f16(af[ks], bf, acc[nt], 0, 0, 0);
        }
    float bv[4];
    #pragma unroll
    for (int r = 0; r < 4; r++) bv[r] = lb[n0 + w * 16 + quad * 4 + r];
    #pragma unroll
    for (int nt = 0; nt < 4; nt++) {
        int pos = m0 + nt * 16 + nn;
        PkU p0, p1;
        p0.h = __builtin_amdgcn_cvt_pkrtz(fmaxf(acc[nt][0] + bv[0], 0.f), fmaxf(acc[nt][1] + bv[1], 0.f));
        p1.h = __builtin_amdgcn_cvt_pkrtz(fmaxf(acc[nt][2] + bv[2], 0.f), fmaxf(acc[nt][3] + bv[3], 0.f));
        *(uint2*)&yh[(size_t)pos * 128 + n0 + w * 16 + quad * 4] = make_uint2(p0.u, p1.u);
    }
}

// ---------- qkv GEMM: grid (352, 6); Q|K rows stride 256, V transposed ----------
__global__ __launch_bounds__(256) void gemm_qkv(
    const f16* __restrict__ A, const f16* __restrict__ W, const float* __restrict__ bias,
    f16* __restrict__ qkh, f16* __restrict__ vt)
{
    __shared__ __align__(16) f16 Alds[64 * 136];
    const int m0 = blockIdx.x * 64, n0 = blockIdx.y * 64;
    const int tid = threadIdx.x;
    const int w = tid >> 6, lane = tid & 63, quad = lane >> 4, nn = lane & 15;

    for (int i = tid; i < 1024; i += 256) {
        int r = i >> 4, c = i & 15;
        *(uint4*)&Alds[r * 136 + c * 8] = *(const uint4*)&A[(size_t)(m0 + r) * 128 + c * 8];
    }
    __syncthreads();

    const int oc = n0 + w * 16 + nn;
    f16x8 af[4];
    #pragma unroll
    for (int ks = 0; ks < 4; ks++)
        af[ks] = *(const f16x8*)&W[(size_t)oc * 128 + ks * 32 + quad * 8];
    f32x4 acc[4] = {};
    #pragma unroll
    for (int ks = 0; ks < 4; ks++)
        #pragma unroll
        for (int nt = 0; nt < 4; nt++) {
            f16x8 bf = *(const f16x8*)&Alds[(nt * 16 + nn) * 136 + ks * 32 + quad * 8];
            acc[nt] = __builtin_amdgcn_mfma_f32_16x16x32_f16(af[ks], bf, acc[nt], 0, 0, 0);
        }
    float bv[4];
    #pragma unroll
    for (int r = 0; r < 4; r++) bv[r] = bias[n0 + w * 16 + quad * 4 + r];

    if (n0 < 256) {
        #pragma unroll
        for (int nt = 0; nt < 4; nt++) {
            int pos = m0 + nt * 16 + nn;
            PkU p0, p1;
            p0.h = __builtin_amdgcn_cvt_pkrtz(acc[nt][0] + bv[0], acc[nt][1] + bv[1]);
            p1.h = __builtin_amdgcn_cvt_pkrtz(acc[nt][2] + bv[2], acc[nt][3] + bv[3]);
            *(uint2*)&qkh[(size_t)pos * 256 + n0 + w * 16 + quad * 4] = make_uint2(p0.u, p1.u);
        }
    } else {
        #pragma unroll
        for (int nt = 0; nt < 4; nt++) {
            int pos = m0 + nt * 16 + nn;
            #pragma unroll
            for (int r = 0; r < 4; r++) {
                int chg = n0 - 256 + w * 16 + quad * 4 + r;
                vt[(size_t)chg * NPAD + pos] = (f16)(acc[nt][r] + bv[r]);
            }
        }
    }
}

// ---------- final projection: grid (352, 2), fp32 out ----------
__global__ __launch_bounds__(256) void gemm_out(
    const f16* __restrict__ A, const f16* __restrict__ W, const float* __restrict__ bias,
    float* __restrict__ outp)
{
    __shared__ __align__(16) f16 Alds[64 * 136];
    const int m0 = blockIdx.x * 64, n0 = blockIdx.y * 64;
    const int tid = threadIdx.x;
    const int w = tid >> 6, lane = tid & 63, quad = lane >> 4, nn = lane & 15;

    for (int i = tid; i < 1024; i += 256) {
        int r = i >> 4, c = i & 15;
        *(uint4*)&Alds[r * 136 + c * 8] = *(const uint4*)&A[(size_t)(m0 + r) * 128 + c * 8];
    }
    __syncthreads();

    const int oc = n0 + w * 16 + nn;
    f16x8 af[4];
    #pragma unroll
    for (int ks = 0; ks < 4; ks++)
        af[ks] = *(const f16x8*)&W[(size_t)oc * 128 + ks * 32 + quad * 8];
    f32x4 acc[4] = {};
    #pragma unroll
    for (int ks = 0; ks < 4; ks++)
        #pragma unroll
        for (int nt = 0; nt < 4; nt++) {
            f16x8 bf = *(const f16x8*)&Alds[(nt * 16 + nn) * 136 + ks * 32 + quad * 8];
            acc[nt] = __builtin_amdgcn_mfma_f32_16x16x32_f16(af[ks], bf, acc[nt], 0, 0, 0);
        }
    float bv[4];
    #pragma unroll
    for (int r = 0; r < 4; r++) bv[r] = bias[n0 + w * 16 + quad * 4 + r];
    #pragma unroll
    for (int nt = 0; nt < 4; nt++) {
        int pos = m0 + nt * 16 + nn;
        f32x4 vv;
        #pragma unroll
        for (int r = 0; r < 4; r++) vv[r] = acc[nt][r] + bv[r];
        *(f32x4*)&outp[(size_t)pos * 128 + n0 + w * 16 + quad * 4] = vv;
    }
}

// ---------- MFMA neighborhood attention: single-wave blocks, one 16-query set per block ----------
// Grid (128, 11, 4): 2x8 query tile, one head. No barriers, no merge: O/lacc private.
// Key-row loop anchored at si0 (25-26 valid rows, no dead chunks). rpb+mask folded into
// S-MFMA accumulator; l via MFMA-with-ones. OOB addrs clamped (finite) + masked to p=0.
__global__ __launch_bounds__(64) void attn_mfma(
    const f16* __restrict__ qkh,   // [N][256] = Q|K, Q pre-scaled by QSC
    const f16* __restrict__ vt,    // [128][NPAD]
    const float* __restrict__ rpbp,
    f16* __restrict__ ao)          // [N][128]
{
    const int i0 = blockIdx.x * 2;
    const int j0 = blockIdx.y * 8;
    const int h  = blockIdx.z;
    const int lane = threadIdx.x;
    const int quad = lane >> 4, nn = lane & 15;

    const int rj0 = min(max(j0 - 12, 0), PP - WIN) & ~1;

    __shared__ f16 Plds[16][40];

    // per-lane query (16 queries: 2 i-rows x 8 j-cols)
    const int qi = i0 + (nn >> 3);
    const int qj = j0 + (nn & 7);
    const int si = min(max(qi - 12, 0), TT - WIN);
    const int sj = min(max(qj - 12, 0), PP - WIN);
    const unsigned cm = 0x1FFFFFFu << (sj - rj0);
    const int dbb = rj0 - qj + 24;
    const f16x8 qf = *(const f16x8*)&qkh[(size_t)(qi * PP + qj) * 256 + h * HD + quad * 8];

    // block-uniform key-row range [si0, si1+24]
    const int si0 = min(max(i0 - 12, 0), TT - WIN);
    const int si1 = min(max(i0 + 1 - 12, 0), TT - WIN);
    const int nchunks = si1 + 25 - si0;   // 25 or 26

    const float* rp_h = rpbp + h * RPBSZ;
    const f16* vbase = vt + (size_t)(h * HD + nn) * NPAD;
    const f16x8 onesv = {(f16)1.f, (f16)1.f, (f16)1.f, (f16)1.f,
                         (f16)1.f, (f16)1.f, (f16)1.f, (f16)1.f};

    f32x4 O0 = {}, O1 = {};   // regs = queries, lane nn = channel
    f32x4 lacc = {};

    const int b0 = min(rj0 + nn, PP - 1);
    const int b1 = min(rj0 + 16 + nn, PP - 1);

    for (int c = 0; c < nchunks; c++) {
        int aa = si0 + c;                                   // in [0, 255]
        const f16* rowK = qkh + (size_t)aa * PP * 256 + 128 + h * HD + quad * 8;
        f16x8 kf0 = *(const f16x8*)(rowK + (size_t)b0 * 256);
        f16x8 kf1 = *(const f16x8*)(rowK + (size_t)b1 * 256);
        const f16* vrow = vbase + aa * PP + rj0 + quad * 8;
        f16x8 vf0 = *(const f16x8u*)vrow;
        f16x8 vf1 = *(const f16x8u*)(vrow + (size_t)16 * NPAD);

        unsigned vm = ((unsigned)(aa - si) <= 24u) ? cm : 0u;
        const float* rp = rp_h + (aa - qi + 24) * RPBW + dbb;
        f32x4 ra = *(const f32x4u*)(rp + quad * 4);
        f32x4 rb = *(const f32x4u*)(rp + 16 + quad * 4);
        f32x4 za, zb;
        #pragma unroll
        for (int r = 0; r < 4; r++) {
            int kl0 = quad * 4 + r;
            za[r] = ((vm >> kl0) & 1u) ? ra[r] : -1e30f;
            zb[r] = ((vm >> (kl0 + 16)) & 1u) ? rb[r] : -1e30f;
        }
        f32x4 s0 = __builtin_amdgcn_mfma_f32_16x16x32_f16(kf0, qf, za, 0, 0, 0);
        f32x4 s1 = __builtin_amdgcn_mfma_f32_16x16x32_f16(kf1, qf, zb, 0, 0, 0);

        float p[8];
        #pragma unroll
        for (int r = 0; r < 4; r++) {
            p[r]     = EXP2(s0[r]);
            p[r + 4] = EXP2(s1[r]);
        }
        PkU a, b, cc, d;
        a.h  = __builtin_amdgcn_cvt_pkrtz(p[0], p[1]);
        b.h  = __builtin_amdgcn_cvt_pkrtz(p[2], p[3]);
        cc.h = __builtin_amdgcn_cvt_pkrtz(p[4], p[5]);
        d.h  = __builtin_amdgcn_cvt_pkrtz(p[6], p[7]);
        *(uint2*)&Plds[nn][quad * 4]      = make_uint2(a.u, b.u);
        *(uint2*)&Plds[nn][16 + quad * 4] = make_uint2(cc.u, d.u);
        f16x8 pf = *(const f16x8*)&Plds[nn][quad * 8];

        O0   = __builtin_amdgcn_mfma_f32_16x16x32_f16(pf, vf0, O0, 0, 0, 0);
        O1   = __builtin_amdgcn_mfma_f32_16x16x32_f16(pf, vf1, O1, 0, 0, 0);
        lacc = __builtin_amdgcn_mfma_f32_16x16x32_f16(pf, onesv, lacc, 0, 0, 0);
    }

    #pragma unroll
    for (int r = 0; r < 4; r++) {
        float li = 1.f / lacc[r];
        int ql = quad * 4 + r;
        int qi2 = i0 + (ql >> 3), qj2 = j0 + (ql & 7);
        size_t base = (size_t)(qi2 * PP + qj2) * CC + h * HD;
        ao[base + nn]      = (f16)(O0[r] * li);
        ao[base + 16 + nn] = (f16)(O1[r] * li);
    }
}

extern "C" void kernel_launch(void* const* d_in, const int* in_sizes, int n_in,
                              void* d_out, int out_size, void* d_ws, size_t ws_size,
                              hipStream_t stream) {
    (void)in_sizes; (void)n_in; (void)out_size; (void)ws_size;
    const float* x    = (const float*)d_in[0];
    const float* cond = (const float*)d_in[1];
    const float* mask = (const float*)d_in[2];
    const float* lw   = (const float*)d_in[3];
    const float* lb   = (const float*)d_in[4];
    const float* qw   = (const float*)d_in[5];
    const float* qb   = (const float*)d_in[6];
    const float* rpb  = (const float*)d_in[7];
    const float* pw   = (const float*)d_in[8];
    const float* pb   = (const float*)d_in[9];
    float* outp       = (float*)d_out;

    float* ws   = (float*)d_ws;
    float* qbs  = ws;                 // 384
    float* b2s  = qbs + 384;          // 384
    float* rpbp = b2s + 384;          // 10240 padded (stray negative-index reads land in qbs/b2s: finite, masked)
    f16* lwh  = (f16*)(rpbp + 10240);             // 128*160
    f16* qwh  = lwh + 20480;                      // 384*128
    f16* pwh  = qwh + 49152;                      // 128*128
    f16* pwt  = pwh + 16384;                      // 128*128 (pw transposed)
    f16* w2h  = pwt + 16384;                      // 384*128
    f16* yh   = w2h + 49152;                      // NN*128
    f16* qkh  = yh + (size_t)NN * 128;            // NN*256 (Q|K)
    f16* vt   = qkh + (size_t)NN * 256;           // 128*NPAD
    f16* ao   = vt + (size_t)128 * NPAD;          // NN*128

    prep<<<192, 256, 0, stream>>>(lw, qw, pw, qb, pb, rpb, lwh, qwh, pwh, pwt, qbs, b2s, rpbp);
    wcomb_mfma<<<dim3(2, 6), 256, 0, stream>>>(pwt, qwh, w2h);
    fusion_gemm<<<dim3(352, 2), 256, 0, stream>>>(x, cond, mask, lwh, lb, yh);
    gemm_qkv<<<dim3(352, 6), 256, 0, stream>>>(yh, qwh, qbs, qkh, vt);
    attn_mfma<<<dim3(TT / 2, PP / 8, HEADS), 64, 0, stream>>>(qkh, vt, rpbp, ao);
    gemm_qkv<<<dim3(352, 6), 256, 0, stream>>>(ao, w2h, b2s, qkh, vt);   // fused proj+qkv
    attn_mfma<<<dim3(TT / 2, PP / 8, HEADS), 64, 0, stream>>>(qkh, vt, rpbp, ao);
    gemm_out<<<dim3(352, 2), 256, 0, stream>>>(ao, pwh, pb, outp);
}

// Round 11
// 264.583 us; speedup vs baseline: 1.0474x; 1.0474x over previous
//
#include <hip/hip_runtime.h>
#include <hip/hip_fp16.h>

#define TT 256
#define PP 88
#define CC 128
#define NN (TT * PP)          // 22528 positions
#define NPAD (NN + 32)
#define HEADS 4
#define HD 32
#define WIN 25
#define RPBW 49
#define RPBSZ (RPBW * RPBW)   // 2401
#define SCALE 0.17677669529663687f   // 1/sqrt(32)
#define LOG2E 1.4426950408889634f
#define QSC (SCALE * LOG2E)          // fold exp->exp2 into Q path

#if __has_builtin(__builtin_amdgcn_exp2f)
#define EXP2(x) __builtin_amdgcn_exp2f(x)
#else
#define EXP2(x) exp2f(x)
#endif

typedef _Float16 f16;
typedef f16 f16x8 __attribute__((ext_vector_type(8)));
typedef f16 f16x8u __attribute__((ext_vector_type(8), aligned(4)));
typedef float f32x4 __attribute__((ext_vector_type(4)));
typedef float f32x4u __attribute__((ext_vector_type(4), aligned(4)));
typedef __fp16 hf16x2 __attribute__((ext_vector_type(2)));
union PkU { hf16x2 h; unsigned u; };

// ---------- prep: repack (b<192) + parallel b2s (192<=b<216) + MFMA wcomb (216<=b<228) ----------
// All three sections read only fp32 inputs -> no intra-launch dependencies.
__global__ __launch_bounds__(256) void prep(
    const float* __restrict__ lw, const float* __restrict__ qw,
    const float* __restrict__ pw, const float* __restrict__ qb,
    const float* __restrict__ pb, const float* __restrict__ rpb,
    f16* __restrict__ lwh, f16* __restrict__ qwh, f16* __restrict__ pwh,
    f16* __restrict__ w2h, float* __restrict__ qbs, float* __restrict__ b2s,
    float* __restrict__ rpbp)
{
    const int b = blockIdx.x;
    if (b < 192) {
        int idx = b * 256 + threadIdx.x;              // covers 49152
        if (idx < 128 * 160) {                        // fusion W: [128][131] -> [128][160] pad
            int r = idx / 160, c = idx - r * 160;
            lwh[idx] = (f16)(c < 131 ? lw[r * 131 + c] : 0.f);
        }
        if (idx < 384 * 128) {                        // qkv W, Q rows scaled by QSC
            float v = qw[idx];
            if (idx < 128 * 128) v *= QSC;
            qwh[idx] = (f16)v;
        }
        if (idx < 128 * 128) pwh[idx] = (f16)pw[idx];
        if (idx < 384) qbs[idx] = qb[idx] * (idx < 128 ? QSC : 1.f);
        if (idx < 10240) rpbp[idx] = (idx < 4 * RPBSZ) ? rpb[idx] * LOG2E : 0.f;
    } else if (b < 216) {
        // b2s[i] = (qb[i] + qw[i,:]·pb) * sc_i ; 16 lanes per output, shuffle-reduce
        int t = (b - 192) * 256 + threadIdx.x;        // [0, 6144)
        int i = t >> 4, l = t & 15;
        if (i < 384) {
            float s = 0.f;
            #pragma unroll
            for (int j = l * 8; j < l * 8 + 8; j++) s += qw[i * 128 + j] * pb[j];
            s += __shfl_xor(s, 1); s += __shfl_xor(s, 2);
            s += __shfl_xor(s, 4); s += __shfl_xor(s, 8);
            if (l == 0) b2s[i] = (qb[i] + s) * (i < 128 ? QSC : 1.f);
        }
    } else {
        // w2h[i][k] = sc_i * sum_j qw[i][j] pw[j][k]; A rows = k (pw^T), B rows = i (qw)
        const int bw = b - 216;                       // 0..11
        const int m0 = (bw & 1) * 64;                 // k-tile
        const int n0 = (bw >> 1) * 64;                // i-tile
        const int tid = threadIdx.x;
        const int w = tid >> 6, lane = tid & 63, quad = lane >> 4, nn = lane & 15;
        const int krow = m0 + w * 16 + nn;
        f16x8 af[4];
        #pragma unroll
        for (int ks = 0; ks < 4; ks++) {
            union { f16 e[8]; f16x8 v; } t;
            #pragma unroll
            for (int e = 0; e < 8; e++)
                t.e[e] = (f16)pw[(ks * 32 + quad * 8 + e) * 128 + krow];
            af[ks] = t.v;
        }
        f32x4 acc[4] = {};
        #pragma unroll
        for (int nt = 0; nt < 4; nt++) {
            int irow = n0 + nt * 16 + nn;
            #pragma unroll
            for (int ks = 0; ks < 4; ks++) {
                const float* qr = &qw[(size_t)irow * 128 + ks * 32 + quad * 8];
                float4 a = *(const float4*)qr, bq = *(const float4*)(qr + 4);
                PkU u0, u1, u2, u3;
                u0.h = __builtin_amdgcn_cvt_pkrtz(a.x, a.y);
                u1.h = __builtin_amdgcn_cvt_pkrtz(a.z, a.w);
                u2.h = __builtin_amdgcn_cvt_pkrtz(bq.x, bq.y);
                u3.h = __builtin_amdgcn_cvt_pkrtz(bq.z, bq.w);
                union { unsigned u[4]; f16x8 v; } bb;
                bb.u[0] = u0.u; bb.u[1] = u1.u; bb.u[2] = u2.u; bb.u[3] = u3.u;
                acc[nt] = __builtin_amdgcn_mfma_f32_16x16x32_f16(af[ks], bb.v, acc[nt], 0, 0, 0);
            }
        }
        #pragma unroll
        for (int nt = 0; nt < 4; nt++) {
            int i = n0 + nt * 16 + nn;
            float sc = (i < 128) ? QSC : 1.f;
            PkU p0, p1;
            p0.h = __builtin_amdgcn_cvt_pkrtz(acc[nt][0] * sc, acc[nt][1] * sc);
            p1.h = __builtin_amdgcn_cvt_pkrtz(acc[nt][2] * sc, acc[nt][3] * sc);
            *(uint2*)&w2h[(size_t)i * 128 + m0 + w * 16 + quad * 4] = make_uint2(p0.u, p1.u);
        }
    }
}

// ---------- fusion GEMM: yh = relu(cat @ lwh^T + lb); grid (352, 2) ----------
__global__ __launch_bounds__(256) void fusion_gemm(
    const float* __restrict__ x, const float* __restrict__ cond, const float* __restrict__ mask,
    const f16* __restrict__ lwh, const float* __restrict__ lb, f16* __restrict__ yh)
{
    __shared__ __align__(16) f16 Alds[64 * 168];
    const int m0 = blockIdx.x * 64, n0 = blockIdx.y * 64;
    const int tid = threadIdx.x;
    const int w = tid >> 6, lane = tid & 63, quad = lane >> 4, nn = lane & 15;

    {   // stage cat rows (f16)
        int r = tid >> 2, cpart = tid & 3;
        size_t pos = m0 + r;
        *(uint4*)&Alds[r * 168 + 128 + cpart * 8] = make_uint4(0, 0, 0, 0);
        const float* xr = x + pos * 128 + cpart * 32;
        #pragma unroll
        for (int t = 0; t < 4; t++) {
            float4 a = *(const float4*)(xr + t * 8);
            float4 b = *(const float4*)(xr + t * 8 + 4);
            PkU p0, p1, p2, p3;
            p0.h = __builtin_amdgcn_cvt_pkrtz(a.x, a.y);
            p1.h = __builtin_amdgcn_cvt_pkrtz(a.z, a.w);
            p2.h = __builtin_amdgcn_cvt_pkrtz(b.x, b.y);
            p3.h = __builtin_amdgcn_cvt_pkrtz(b.z, b.w);
            *(uint4*)&Alds[r * 168 + cpart * 32 + t * 8] = make_uint4(p0.u, p1.u, p2.u, p3.u);
        }
        if (cpart == 0) {
            Alds[r * 168 + 128] = (f16)cond[pos * 2];
            Alds[r * 168 + 129] = (f16)cond[pos * 2 + 1];
            Alds[r * 168 + 130] = (f16)mask[pos];
        }
    }
    __syncthreads();

    const int oc = n0 + w * 16 + nn;
    f16x8 af[5];
    #pragma unroll
    for (int ks = 0; ks < 5; ks++)
        af[ks] = *(const f16x8*)&lwh[(size_t)oc * 160 + ks * 32 + quad * 8];
    f32x4 acc[4] = {};
    #pragma unroll
    for (int ks = 0; ks < 5; ks++)
        #pragma unroll
        for (int nt = 0; nt < 4; nt++) {
            f16x8 bf = *(const f16x8*)&Alds[(nt * 16 + nn) * 168 + ks * 32 + quad * 8];
            acc[nt] = __builtin_amdgcn_mfma_f32_16x16x32_f16(af[ks], bf, acc[nt], 0, 0, 0);
        }
    float bv[4];
    #pragma unroll
    for (int r = 0; r < 4; r++) bv[r] = lb[n0 + w * 16 + quad * 4 + r];
    #pragma unroll
    for (int nt = 0; nt < 4; nt++) {
        int pos = m0 + nt * 16 + nn;
        PkU p0, p1;
        p0.h = __builtin_amdgcn_cvt_pkrtz(fmaxf(acc[nt][0] + bv[0], 0.f), fmaxf(acc[nt][1] + bv[1], 0.f));
        p1.h = __builtin_amdgcn_cvt_pkrtz(fmaxf(acc[nt][2] + bv[2], 0.f), fmaxf(acc[nt][3] + bv[3], 0.f));
        *(uint2*)&yh[(size_t)pos * 128 + n0 + w * 16 + quad * 4] = make_uint2(p0.u, p1.u);
    }
}

// ---------- qkv GEMM: grid (352, 6); Q|K rows stride 256, V transposed ----------
__global__ __launch_bounds__(256) void gemm_qkv(
    const f16* __restrict__ A, const f16* __restrict__ W, const float* __restrict__ bias,
    f16* __restrict__ qkh, f16* __restrict__ vt)
{
    __shared__ __align__(16) f16 Alds[64 * 136];
    const int m0 = blockIdx.x * 64, n0 = blockIdx.y * 64;
    const int tid = threadIdx.x;
    const int w = tid >> 6, lane = tid & 63, quad = lane >> 4, nn = lane & 15;

    for (int i = tid; i < 1024; i += 256) {
        int r = i >> 4, c = i & 15;
        *(uint4*)&Alds[r * 136 + c * 8] = *(const uint4*)&A[(size_t)(m0 + r) * 128 + c * 8];
    }
    __syncthreads();

    const int oc = n0 + w * 16 + nn;
    f16x8 af[4];
    #pragma unroll
    for (int ks = 0; ks < 4; ks++)
        af[ks] = *(const f16x8*)&W[(size_t)oc * 128 + ks * 32 + quad * 8];
    f32x4 acc[4] = {};
    #pragma unroll
    for (int ks = 0; ks < 4; ks++)
        #pragma unroll
        for (int nt = 0; nt < 4; nt++) {
            f16x8 bf = *(const f16x8*)&Alds[(nt * 16 + nn) * 136 + ks * 32 + quad * 8];
            acc[nt] = __builtin_amdgcn_mfma_f32_16x16x32_f16(af[ks], bf, acc[nt], 0, 0, 0);
        }
    float bv[4];
    #pragma unroll
    for (int r = 0; r < 4; r++) bv[r] = bias[n0 + w * 16 + quad * 4 + r];

    if (n0 < 256) {
        #pragma unroll
        for (int nt = 0; nt < 4; nt++) {
            int pos = m0 + nt * 16 + nn;
            PkU p0, p1;
            p0.h = __builtin_amdgcn_cvt_pkrtz(acc[nt][0] + bv[0], acc[nt][1] + bv[1]);
            p1.h = __builtin_amdgcn_cvt_pkrtz(acc[nt][2] + bv[2], acc[nt][3] + bv[3]);
            *(uint2*)&qkh[(size_t)pos * 256 + n0 + w * 16 + quad * 4] = make_uint2(p0.u, p1.u);
        }
    } else {
        #pragma unroll
        for (int nt = 0; nt < 4; nt++) {
            int pos = m0 + nt * 16 + nn;
            #pragma unroll
            for (int r = 0; r < 4; r++) {
                int chg = n0 - 256 + w * 16 + quad * 4 + r;
                vt[(size_t)chg * NPAD + pos] = (f16)(acc[nt][r] + bv[r]);
            }
        }
    }
}

// ---------- final projection: grid (352, 2), fp32 out ----------
__global__ __launch_bounds__(256) void gemm_out(
    const f16* __restrict__ A, const f16* __restrict__ W, const float* __restrict__ bias,
    float* __restrict__ outp)
{
    __shared__ __align__(16) f16 Alds[64 * 136];
    const int m0 = blockIdx.x * 64, n0 = blockIdx.y * 64;
    const int tid = threadIdx.x;
    const int w = tid >> 6, lane = tid & 63, quad = lane >> 4, nn = lane & 15;

    for (int i = tid; i < 1024; i += 256) {
        int r = i >> 4, c = i & 15;
        *(uint4*)&Alds[r * 136 + c * 8] = *(const uint4*)&A[(size_t)(m0 + r) * 128 + c * 8];
    }
    __syncthreads();

    const int oc = n0 + w * 16 + nn;
    f16x8 af[4];
    #pragma unroll
    for (int ks = 0; ks < 4; ks++)
        af[ks] = *(const f16x8*)&W[(size_t)oc * 128 + ks * 32 + quad * 8];
    f32x4 acc[4] = {};
    #pragma unroll
    for (int ks = 0; ks < 4; ks++)
        #pragma unroll
        for (int nt = 0; nt < 4; nt++) {
            f16x8 bf = *(const f16x8*)&Alds[(nt * 16 + nn) * 136 + ks * 32 + quad * 8];
            acc[nt] = __builtin_amdgcn_mfma_f32_16x16x32_f16(af[ks], bf, acc[nt], 0, 0, 0);
        }
    float bv[4];
    #pragma unroll
    for (int r = 0; r < 4; r++) bv[r] = bias[n0 + w * 16 + quad * 4 + r];
    #pragma unroll
    for (int nt = 0; nt < 4; nt++) {
        int pos = m0 + nt * 16 + nn;
        f32x4 vv;
        #pragma unroll
        for (int r = 0; r < 4; r++) vv[r] = acc[nt][r] + bv[r];
        *(f32x4*)&outp[(size_t)pos * 128 + n0 + w * 16 + quad * 4] = vv;
    }
}

// ---------- MFMA neighborhood attention: 8x8 query tile, wave = one 16-query set ----------
// Grid (32, 11, 4), 256 thr = 4 waves; wave qs owns queries [qs*16, qs*16+16) (2 query
// rows) for head blockIdx.z: NO barriers, NO merge. Per-wave si-anchored key-row loop
// (25-26 chunks, no dead rows). rpb+mask folded into S-MFMA accumulator (exp2 domain);
// l via MFMA-with-ones. OOB key addrs clamped (finite) + masked to p=0.
__global__ __launch_bounds__(256) void attn_mfma(
    const f16* __restrict__ qkh,   // [N][256] = Q|K, Q pre-scaled by QSC
    const f16* __restrict__ vt,    // [128][NPAD]
    const float* __restrict__ rpbp,
    f16* __restrict__ ao)          // [N][128]
{
    const int i0 = blockIdx.x * 8;
    const int j0 = blockIdx.y * 8;
    const int h  = blockIdx.z;
    const int tid = threadIdx.x;
    const int qs = tid >> 6, lane = tid & 63;
    const int quad = lane >> 4, nn = lane & 15;

    const int rj0 = min(max(j0 - 12, 0), PP - WIN) & ~1;

    __shared__ f16 Plds[4][16][40];

    // per-lane query (lane nn = query within qset; 2 i-rows x 8 j-cols)
    const int qi = i0 + qs * 2 + (nn >> 3);
    const int qj = j0 + (nn & 7);
    const int si = min(max(qi - 12, 0), TT - WIN);
    const int sj = min(max(qj - 12, 0), PP - WIN);
    const unsigned cm = 0x1FFFFFFu << (sj - rj0);   // shift <= 7
    const int dbb = rj0 - qj + 24;
    const f16x8 qf = *(const f16x8*)&qkh[(size_t)(qi * PP + qj) * 256 + h * HD + quad * 8];

    // wave-uniform key-row range for this qset's 2 query rows
    const int wi0 = i0 + qs * 2;
    const int wsi0 = min(max(wi0 - 12, 0), TT - WIN);
    const int wsiL = min(max(wi0 + 1 - 12, 0), TT - WIN);
    const int nch = wsiL + 25 - wsi0;               // 25 or 26

    const float* rp_h = rpbp + h * RPBSZ;
    const f16* vbase = vt + (size_t)(h * HD + nn) * NPAD;
    const f16x8 onesv = {(f16)1.f, (f16)1.f, (f16)1.f, (f16)1.f,
                         (f16)1.f, (f16)1.f, (f16)1.f, (f16)1.f};

    f32x4 O0 = {}, O1 = {};   // regs = queries (quad*4+r), lane nn = channel
    f32x4 lacc = {};

    const int b0 = min(rj0 + nn, PP - 1);
    const int b1 = min(rj0 + 16 + nn, PP - 1);

    for (int c = 0; c < nch; c++) {
        int aa = wsi0 + c;                                  // in [0, 255]
        const f16* rowK = qkh + (size_t)aa * PP * 256 + 128 + h * HD + quad * 8;
        f16x8 kf0 = *(const f16x8*)(rowK + (size_t)b0 * 256);
        f16x8 kf1 = *(const f16x8*)(rowK + (size_t)b1 * 256);
        const f16* vrow = vbase + aa * PP + rj0 + quad * 8;
        f16x8 vf0 = *(const f16x8u*)vrow;
        f16x8 vf1 = *(const f16x8u*)(vrow + (size_t)16 * NPAD);

        unsigned vm = ((unsigned)(aa - si) <= 24u) ? cm : 0u;
        const float* rp = rp_h + (aa - qi + 24) * RPBW + dbb;
        f32x4 ra = *(const f32x4u*)(rp + quad * 4);
        f32x4 rb = *(const f32x4u*)(rp + 16 + quad * 4);
        f32x4 za, zb;
        #pragma unroll
        for (int r = 0; r < 4; r++) {
            int kl0 = quad * 4 + r;
            za[r] = ((vm >> kl0) & 1u) ? ra[r] : -1e30f;
            zb[r] = ((vm >> (kl0 + 16)) & 1u) ? rb[r] : -1e30f;
        }
        f32x4 s0 = __builtin_amdgcn_mfma_f32_16x16x32_f16(kf0, qf, za, 0, 0, 0);
        f32x4 s1 = __builtin_amdgcn_mfma_f32_16x16x32_f16(kf1, qf, zb, 0, 0, 0);

        float p[8];
        #pragma unroll
        for (int r = 0; r < 4; r++) {
            p[r]     = EXP2(s0[r]);
            p[r + 4] = EXP2(s1[r]);
        }
        PkU a, b, cc, d;
        a.h  = __builtin_amdgcn_cvt_pkrtz(p[0], p[1]);
        b.h  = __builtin_amdgcn_cvt_pkrtz(p[2], p[3]);
        cc.h = __builtin_amdgcn_cvt_pkrtz(p[4], p[5]);
        d.h  = __builtin_amdgcn_cvt_pkrtz(p[6], p[7]);
        *(uint2*)&Plds[qs][nn][quad * 4]      = make_uint2(a.u, b.u);
        *(uint2*)&Plds[qs][nn][16 + quad * 4] = make_uint2(cc.u, d.u);
        f16x8 pf = *(const f16x8*)&Plds[qs][nn][quad * 8];

        O0   = __builtin_amdgcn_mfma_f32_16x16x32_f16(pf, vf0, O0, 0, 0, 0);
        O1   = __builtin_amdgcn_mfma_f32_16x16x32_f16(pf, vf1, O1, 0, 0, 0);
        lacc = __builtin_amdgcn_mfma_f32_16x16x32_f16(pf, onesv, lacc, 0, 0, 0);
    }

    #pragma unroll
    for (int r = 0; r < 4; r++) {
        float li = 1.f / lacc[r];
        int qq = quad * 4 + r;                      // query within qset
        int qi2 = i0 + qs * 2 + (qq >> 3), qj2 = j0 + (qq & 7);
        size_t base = (size_t)(qi2 * PP + qj2) * CC + h * HD;
        ao[base + nn]      = (f16)(O0[r] * li);
        ao[base + 16 + nn] = (f16)(O1[r] * li);
    }
}

extern "C" void kernel_launch(void* const* d_in, const int* in_sizes, int n_in,
                              void* d_out, int out_size, void* d_ws, size_t ws_size,
                              hipStream_t stream) {
    (void)in_sizes; (void)n_in; (void)out_size; (void)ws_size;
    const float* x    = (const float*)d_in[0];
    const float* cond = (const float*)d_in[1];
    const float* mask = (const float*)d_in[2];
    const float* lw   = (const float*)d_in[3];
    const float* lb   = (const float*)d_in[4];
    const float* qw   = (const float*)d_in[5];
    const float* qb   = (const float*)d_in[6];
    const float* rpb  = (const float*)d_in[7];
    const float* pw   = (const float*)d_in[8];
    const float* pb   = (const float*)d_in[9];
    float* outp       = (float*)d_out;

    float* ws   = (float*)d_ws;
    float* qbs  = ws;                 // 384
    float* b2s  = qbs + 384;          // 384
    float* rpbp = b2s + 384;          // 10240 padded (stray negative-index reads land in qbs/b2s: finite, masked)
    f16* lwh  = (f16*)(rpbp + 10240);             // 128*160
    f16* qwh  = lwh + 20480;                      // 384*128
    f16* pwh  = qwh + 49152;                      // 128*128
    f16* w2h  = pwh + 16384;                      // 384*128
    f16* yh   = w2h + 49152;                      // NN*128
    f16* qkh  = yh + (size_t)NN * 128;            // NN*256 (Q|K)
    f16* vt   = qkh + (size_t)NN * 256;           // 128*NPAD
    f16* ao   = vt + (size_t)128 * NPAD;          // NN*128

    prep<<<228, 256, 0, stream>>>(lw, qw, pw, qb, pb, rpb, lwh, qwh, pwh, w2h, qbs, b2s, rpbp);
    fusion_gemm<<<dim3(352, 2), 256, 0, stream>>>(x, cond, mask, lwh, lb, yh);
    gemm_qkv<<<dim3(352, 6), 256, 0, stream>>>(yh, qwh, qbs, qkh, vt);
    attn_mfma<<<dim3(TT / 8, PP / 8, HEADS), 256, 0, stream>>>(qkh, vt, rpbp, ao);
    gemm_qkv<<<dim3(352, 6), 256, 0, stream>>>(ao, w2h, b2s, qkh, vt);   // fused proj+qkv
    attn_mfma<<<dim3(TT / 8, PP / 8, HEADS), 256, 0, stream>>>(qkh, vt, rpbp, ao);
    gemm_out<<<dim3(352, 2), 256, 0, stream>>>(ao, pwh, pb, outp);
}

// Round 12
// 218.650 us; speedup vs baseline: 1.2675x; 1.2101x over previous
//
#include <hip/hip_runtime.h>
#include <hip/hip_fp16.h>

#define TT 256
#define PP 88
#define CC 128
#define NN (TT * PP)          // 22528 positions
#define NPAD (NN + 32)
#define HEADS 4
#define HD 32
#define WIN 25
#define RPBW 49
#define RPBSZ (RPBW * RPBW)   // 2401
#define SCALE 0.17677669529663687f   // 1/sqrt(32)
#define LOG2E 1.4426950408889634f
#define QSC (SCALE * LOG2E)          // fold exp->exp2 into Q path

#if __has_builtin(__builtin_amdgcn_exp2f)
#define EXP2(x) __builtin_amdgcn_exp2f(x)
#else
#define EXP2(x) exp2f(x)
#endif

typedef _Float16 f16;
typedef f16 f16x8 __attribute__((ext_vector_type(8)));
typedef f16 f16x8u __attribute__((ext_vector_type(8), aligned(4)));
typedef float f32x4 __attribute__((ext_vector_type(4)));
typedef float f32x4u __attribute__((ext_vector_type(4), aligned(4)));
typedef __fp16 hf16x2 __attribute__((ext_vector_type(2)));
union PkU { hf16x2 h; unsigned u; };

// ---------- prep: repack (b<192) + parallel b2s (192<=b<216) + MFMA wcomb (216<=b<228) ----------
__global__ __launch_bounds__(256) void prep(
    const float* __restrict__ lw, const float* __restrict__ qw,
    const float* __restrict__ pw, const float* __restrict__ qb,
    const float* __restrict__ pb, const float* __restrict__ rpb,
    f16* __restrict__ lwh, f16* __restrict__ qwh, f16* __restrict__ pwh,
    f16* __restrict__ w2h, float* __restrict__ qbs, float* __restrict__ b2s,
    float* __restrict__ rpbp)
{
    const int b = blockIdx.x;
    if (b < 192) {
        int idx = b * 256 + threadIdx.x;              // covers 49152
        if (idx < 128 * 160) {                        // fusion W: [128][131] -> [128][160] pad
            int r = idx / 160, c = idx - r * 160;
            lwh[idx] = (f16)(c < 131 ? lw[r * 131 + c] : 0.f);
        }
        if (idx < 384 * 128) {                        // qkv W, Q rows scaled by QSC
            float v = qw[idx];
            if (idx < 128 * 128) v *= QSC;
            qwh[idx] = (f16)v;
        }
        if (idx < 128 * 128) pwh[idx] = (f16)pw[idx];
        if (idx < 384) qbs[idx] = qb[idx] * (idx < 128 ? QSC : 1.f);
        if (idx < 10240) rpbp[idx] = (idx < 4 * RPBSZ) ? rpb[idx] * LOG2E : 0.f;
    } else if (b < 216) {
        // b2s[i] = (qb[i] + qw[i,:]·pb) * sc_i ; 16 lanes per output, shuffle-reduce
        int t = (b - 192) * 256 + threadIdx.x;        // [0, 6144)
        int i = t >> 4, l = t & 15;
        if (i < 384) {
            float s = 0.f;
            #pragma unroll
            for (int j = l * 8; j < l * 8 + 8; j++) s += qw[i * 128 + j] * pb[j];
            s += __shfl_xor(s, 1); s += __shfl_xor(s, 2);
            s += __shfl_xor(s, 4); s += __shfl_xor(s, 8);
            if (l == 0) b2s[i] = (qb[i] + s) * (i < 128 ? QSC : 1.f);
        }
    } else {
        // w2h[i][k] = sc_i * sum_j qw[i][j] pw[j][k]
        const int bw = b - 216;                       // 0..11
        const int m0 = (bw & 1) * 64;                 // k-tile
        const int n0 = (bw >> 1) * 64;                // i-tile
        const int tid = threadIdx.x;
        const int w = tid >> 6, lane = tid & 63, quad = lane >> 4, nn = lane & 15;
        const int krow = m0 + w * 16 + nn;
        f16x8 af[4];
        #pragma unroll
        for (int ks = 0; ks < 4; ks++) {
            union { f16 e[8]; f16x8 v; } t;
            #pragma unroll
            for (int e = 0; e < 8; e++)
                t.e[e] = (f16)pw[(ks * 32 + quad * 8 + e) * 128 + krow];
            af[ks] = t.v;
        }
        f32x4 acc[4] = {};
        #pragma unroll
        for (int nt = 0; nt < 4; nt++) {
            int irow = n0 + nt * 16 + nn;
            #pragma unroll
            for (int ks = 0; ks < 4; ks++) {
                const float* qr = &qw[(size_t)irow * 128 + ks * 32 + quad * 8];
                float4 a = *(const float4*)qr, bq = *(const float4*)(qr + 4);
                PkU u0, u1, u2, u3;
                u0.h = __builtin_amdgcn_cvt_pkrtz(a.x, a.y);
                u1.h = __builtin_amdgcn_cvt_pkrtz(a.z, a.w);
                u2.h = __builtin_amdgcn_cvt_pkrtz(bq.x, bq.y);
                u3.h = __builtin_amdgcn_cvt_pkrtz(bq.z, bq.w);
                union { unsigned u[4]; f16x8 v; } bb;
                bb.u[0] = u0.u; bb.u[1] = u1.u; bb.u[2] = u2.u; bb.u[3] = u3.u;
                acc[nt] = __builtin_amdgcn_mfma_f32_16x16x32_f16(af[ks], bb.v, acc[nt], 0, 0, 0);
            }
        }
        #pragma unroll
        for (int nt = 0; nt < 4; nt++) {
            int i = n0 + nt * 16 + nn;
            float sc = (i < 128) ? QSC : 1.f;
            PkU p0, p1;
            p0.h = __builtin_amdgcn_cvt_pkrtz(acc[nt][0] * sc, acc[nt][1] * sc);
            p1.h = __builtin_amdgcn_cvt_pkrtz(acc[nt][2] * sc, acc[nt][3] * sc);
            *(uint2*)&w2h[(size_t)i * 128 + m0 + w * 16 + quad * 4] = make_uint2(p0.u, p1.u);
        }
    }
}

// ---------- fusion GEMM: yh = relu(cat @ lwh^T + lb); grid (352, 2) ----------
__global__ __launch_bounds__(256) void fusion_gemm(
    const float* __restrict__ x, const float* __restrict__ cond, const float* __restrict__ mask,
    const f16* __restrict__ lwh, const float* __restrict__ lb, f16* __restrict__ yh)
{
    __shared__ __align__(16) f16 Alds[64 * 168];
    const int m0 = blockIdx.x * 64, n0 = blockIdx.y * 64;
    const int tid = threadIdx.x;
    const int w = tid >> 6, lane = tid & 63, quad = lane >> 4, nn = lane & 15;

    {   // stage cat rows (f16)
        int r = tid >> 2, cpart = tid & 3;
        size_t pos = m0 + r;
        *(uint4*)&Alds[r * 168 + 128 + cpart * 8] = make_uint4(0, 0, 0, 0);
        const float* xr = x + pos * 128 + cpart * 32;
        #pragma unroll
        for (int t = 0; t < 4; t++) {
            float4 a = *(const float4*)(xr + t * 8);
            float4 b = *(const float4*)(xr + t * 8 + 4);
            PkU p0, p1, p2, p3;
            p0.h = __builtin_amdgcn_cvt_pkrtz(a.x, a.y);
            p1.h = __builtin_amdgcn_cvt_pkrtz(a.z, a.w);
            p2.h = __builtin_amdgcn_cvt_pkrtz(b.x, b.y);
            p3.h = __builtin_amdgcn_cvt_pkrtz(b.z, b.w);
            *(uint4*)&Alds[r * 168 + cpart * 32 + t * 8] = make_uint4(p0.u, p1.u, p2.u, p3.u);
        }
        if (cpart == 0) {
            Alds[r * 168 + 128] = (f16)cond[pos * 2];
            Alds[r * 168 + 129] = (f16)cond[pos * 2 + 1];
            Alds[r * 168 + 130] = (f16)mask[pos];
        }
    }
    __syncthreads();

    const int oc = n0 + w * 16 + nn;
    f16x8 af[5];
    #pragma unroll
    for (int ks = 0; ks < 5; ks++)
        af[ks] = *(const f16x8*)&lwh[(size_t)oc * 160 + ks * 32 + quad * 8];
    f32x4 acc[4] = {};
    #pragma unroll
    for (int ks = 0; ks < 5; ks++)
        #pragma unroll
        for (int nt = 0; nt < 4; nt++) {
            f16x8 bf = *(const f16x8*)&Alds[(nt * 16 + nn) * 168 + ks * 32 + quad * 8];
            acc[nt] = __builtin_amdgcn_mfma_f32_16x16x32_f16(af[ks], bf, acc[nt], 0, 0, 0);
        }
    float bv[4];
    #pragma unroll
    for (int r = 0; r < 4; r++) bv[r] = lb[n0 + w * 16 + quad * 4 + r];
    #pragma unroll
    for (int nt = 0; nt < 4; nt++) {
        int pos = m0 + nt * 16 + nn;
        PkU p0, p1;
        p0.h = __builtin_amdgcn_cvt_pkrtz(fmaxf(acc[nt][0] + bv[0], 0.f), fmaxf(acc[nt][1] + bv[1], 0.f));
        p1.h = __builtin_amdgcn_cvt_pkrtz(fmaxf(acc[nt][2] + bv[2], 0.f), fmaxf(acc[nt][3] + bv[3], 0.f));
        *(uint2*)&yh[(size_t)pos * 128 + n0 + w * 16 + quad * 4] = make_uint2(p0.u, p1.u);
    }
}

// ---------- qkv GEMM: grid (352, 6); Q|K rows stride 256, V transposed ----------
__global__ __launch_bounds__(256) void gemm_qkv(
    const f16* __restrict__ A, const f16* __restrict__ W, const float* __restrict__ bias,
    f16* __restrict__ qkh, f16* __restrict__ vt)
{
    __shared__ __align__(16) f16 Alds[64 * 136];
    const int m0 = blockIdx.x * 64, n0 = blockIdx.y * 64;
    const int tid = threadIdx.x;
    const int w = tid >> 6, lane = tid & 63, quad = lane >> 4, nn = lane & 15;

    for (int i = tid; i < 1024; i += 256) {
        int r = i >> 4, c = i & 15;
        *(uint4*)&Alds[r * 136 + c * 8] = *(const uint4*)&A[(size_t)(m0 + r) * 128 + c * 8];
    }
    __syncthreads();

    const int oc = n0 + w * 16 + nn;
    f16x8 af[4];
    #pragma unroll
    for (int ks = 0; ks < 4; ks++)
        af[ks] = *(const f16x8*)&W[(size_t)oc * 128 + ks * 32 + quad * 8];
    f32x4 acc[4] = {};
    #pragma unroll
    for (int ks = 0; ks < 4; ks++)
        #pragma unroll
        for (int nt = 0; nt < 4; nt++) {
            f16x8 bf = *(const f16x8*)&Alds[(nt * 16 + nn) * 136 + ks * 32 + quad * 8];
            acc[nt] = __builtin_amdgcn_mfma_f32_16x16x32_f16(af[ks], bf, acc[nt], 0, 0, 0);
        }
    float bv[4];
    #pragma unroll
    for (int r = 0; r < 4; r++) bv[r] = bias[n0 + w * 16 + quad * 4 + r];

    if (n0 < 256) {
        #pragma unroll
        for (int nt = 0; nt < 4; nt++) {
            int pos = m0 + nt * 16 + nn;
            PkU p0, p1;
            p0.h = __builtin_amdgcn_cvt_pkrtz(acc[nt][0] + bv[0], acc[nt][1] + bv[1]);
            p1.h = __builtin_amdgcn_cvt_pkrtz(acc[nt][2] + bv[2], acc[nt][3] + bv[3]);
            *(uint2*)&qkh[(size_t)pos * 256 + n0 + w * 16 + quad * 4] = make_uint2(p0.u, p1.u);
        }
    } else {
        #pragma unroll
        for (int nt = 0; nt < 4; nt++) {
            int pos = m0 + nt * 16 + nn;
            #pragma unroll
            for (int r = 0; r < 4; r++) {
                int chg = n0 - 256 + w * 16 + quad * 4 + r;
                vt[(size_t)chg * NPAD + pos] = (f16)(acc[nt][r] + bv[r]);
            }
        }
    }
}

// ---------- final projection: grid (352, 2), fp32 out ----------
__global__ __launch_bounds__(256) void gemm_out(
    const f16* __restrict__ A, const f16* __restrict__ W, const float* __restrict__ bias,
    float* __restrict__ outp)
{
    __shared__ __align__(16) f16 Alds[64 * 136];
    const int m0 = blockIdx.x * 64, n0 = blockIdx.y * 64;
    const int tid = threadIdx.x;
    const int w = tid >> 6, lane = tid & 63, quad = lane >> 4, nn = lane & 15;

    for (int i = tid; i < 1024; i += 256) {
        int r = i >> 4, c = i & 15;
        *(uint4*)&Alds[r * 136 + c * 8] = *(const uint4*)&A[(size_t)(m0 + r) * 128 + c * 8];
    }
    __syncthreads();

    const int oc = n0 + w * 16 + nn;
    f16x8 af[4];
    #pragma unroll
    for (int ks = 0; ks < 4; ks++)
        af[ks] = *(const f16x8*)&W[(size_t)oc * 128 + ks * 32 + quad * 8];
    f32x4 acc[4] = {};
    #pragma unroll
    for (int ks = 0; ks < 4; ks++)
        #pragma unroll
        for (int nt = 0; nt < 4; nt++) {
            f16x8 bf = *(const f16x8*)&Alds[(nt * 16 + nn) * 136 + ks * 32 + quad * 8];
            acc[nt] = __builtin_amdgcn_mfma_f32_16x16x32_f16(af[ks], bf, acc[nt], 0, 0, 0);
        }
    float bv[4];
    #pragma unroll
    for (int r = 0; r < 4; r++) bv[r] = bias[n0 + w * 16 + quad * 4 + r];
    #pragma unroll
    for (int nt = 0; nt < 4; nt++) {
        int pos = m0 + nt * 16 + nn;
        f32x4 vv;
        #pragma unroll
        for (int r = 0; r < 4; r++) vv[r] = acc[nt][r] + bv[r];
        *(f32x4*)&outp[(size_t)pos * 128 + n0 + w * 16 + quad * 4] = vv;
    }
}

// ---------- MFMA neighborhood attention: 8x8 query tile, 2 waves key-split, pipelined ----------
// Wave w handles key rows [w*16, w*16+16) for all 4 qsets (K/V loads amortized 4x).
// Next chunk's K/V fragments prefetched before processing the current chunk (the
// one-row overshoot reads land in vt/ao workspace: in-bounds, masked, unused).
// rpb+mask folded into S-MFMA accumulator (exp2 domain); l via MFMA-with-ones.
__global__ __launch_bounds__(128) void attn_mfma(
    const f16* __restrict__ qkh,   // [N][256] = Q|K, Q pre-scaled by QSC
    const f16* __restrict__ vt,    // [128][NPAD]
    const float* __restrict__ rpbp,
    f16* __restrict__ ao)          // [N][128]
{
    const int i0 = blockIdx.x * 8;
    const int j0 = blockIdx.y * 8;
    const int h  = blockIdx.z;
    const int tid = threadIdx.x;
    const int w = tid >> 6, lane = tid & 63;
    const int quad = lane >> 4, nn = lane & 15;

    const int ri0 = min(max(i0 - 12, 0), TT - 32);
    const int rj0 = min(max(j0 - 12, 0), PP - WIN) & ~1;

    __shared__ f16 Plds[2][16][40];
    __shared__ __align__(16) float Olds[64][48];   // wave-1 partials: 32 O + 16 lacc

    int qi_[4], si_[4], dbb_[4];
    unsigned cm_[4];
    f16x8 qf[4];
    #pragma unroll
    for (int qs = 0; qs < 4; qs++) {
        int ql = qs * 16 + nn;
        int qi = i0 + (ql >> 3), qj = j0 + (ql & 7);
        int si = min(max(qi - 12, 0), TT - WIN);
        int sj = min(max(qj - 12, 0), PP - WIN);
        qi_[qs] = qi; si_[qs] = si;
        cm_[qs] = 0x1FFFFFFu << (sj - rj0);       // shift <= 7
        dbb_[qs] = rj0 - qj + 24;
        qf[qs] = *(const f16x8*)&qkh[(size_t)(qi * PP + qj) * 256 + h * HD + quad * 8];
    }
    const float* rp_h = rpbp + h * RPBSZ;
    const f16* vbase = vt + (size_t)(h * HD + nn) * NPAD;
    const f16x8 onesv = {(f16)1.f, (f16)1.f, (f16)1.f, (f16)1.f,
                         (f16)1.f, (f16)1.f, (f16)1.f, (f16)1.f};

    f32x4 O[4][2] = {};    // [qset][ch-half]; regs = queries, lane nn = channel
    f32x4 lacc[4] = {};    // regs = queries

    const int b0 = min(rj0 + nn, PP - 1);
    const int b1 = min(rj0 + 16 + nn, PP - 1);
    const size_t koff = 128 + h * HD + quad * 8;

    // prologue: load chunk w*16
    int aa = ri0 + w * 16;
    const f16* rowK = qkh + (size_t)aa * PP * 256 + koff;
    f16x8 kf0 = *(const f16x8*)(rowK + (size_t)b0 * 256);
    f16x8 kf1 = *(const f16x8*)(rowK + (size_t)b1 * 256);
    const f16* vrow = vbase + aa * PP + rj0 + quad * 8;
    f16x8 vf0 = *(const f16x8u*)vrow;
    f16x8 vf1 = *(const f16x8u*)(vrow + (size_t)16 * NPAD);

    for (int c = 0; c < 16; c++) {
        // prefetch chunk aa+1 (last iteration overshoots into vt/ao scratch: unused)
        const f16* rowKn = qkh + (size_t)(aa + 1) * PP * 256 + koff;
        f16x8 nkf0 = *(const f16x8*)(rowKn + (size_t)b0 * 256);
        f16x8 nkf1 = *(const f16x8*)(rowKn + (size_t)b1 * 256);
        const f16* vrown = vbase + (aa + 1) * PP + rj0 + quad * 8;
        f16x8 nvf0 = *(const f16x8u*)vrown;
        f16x8 nvf1 = *(const f16x8u*)(vrown + (size_t)16 * NPAD);

        #pragma unroll
        for (int qs = 0; qs < 4; qs++) {
            unsigned vm = ((unsigned)(aa - si_[qs]) <= 24u) ? cm_[qs] : 0u;
            const float* rp = rp_h + (aa - qi_[qs] + 24) * RPBW + dbb_[qs];
            f32x4 ra = *(const f32x4u*)(rp + quad * 4);
            f32x4 rb = *(const f32x4u*)(rp + 16 + quad * 4);
            f32x4 za, zb;
            #pragma unroll
            for (int r = 0; r < 4; r++) {
                int kl0 = quad * 4 + r;
                za[r] = ((vm >> kl0) & 1u) ? ra[r] : -1e30f;
                zb[r] = ((vm >> (kl0 + 16)) & 1u) ? rb[r] : -1e30f;
            }
            f32x4 s0 = __builtin_amdgcn_mfma_f32_16x16x32_f16(kf0, qf[qs], za, 0, 0, 0);
            f32x4 s1 = __builtin_amdgcn_mfma_f32_16x16x32_f16(kf1, qf[qs], zb, 0, 0, 0);

            float p[8];
            #pragma unroll
            for (int r = 0; r < 4; r++) {
                p[r]     = EXP2(s0[r]);
                p[r + 4] = EXP2(s1[r]);
            }
            PkU a, b, cc, d;
            a.h  = __builtin_amdgcn_cvt_pkrtz(p[0], p[1]);
            b.h  = __builtin_amdgcn_cvt_pkrtz(p[2], p[3]);
            cc.h = __builtin_amdgcn_cvt_pkrtz(p[4], p[5]);
            d.h  = __builtin_amdgcn_cvt_pkrtz(p[6], p[7]);
            *(uint2*)&Plds[w][nn][quad * 4]      = make_uint2(a.u, b.u);
            *(uint2*)&Plds[w][nn][16 + quad * 4] = make_uint2(cc.u, d.u);
            f16x8 pf = *(const f16x8*)&Plds[w][nn][quad * 8];

            O[qs][0] = __builtin_amdgcn_mfma_f32_16x16x32_f16(pf, vf0, O[qs][0], 0, 0, 0);
            O[qs][1] = __builtin_amdgcn_mfma_f32_16x16x32_f16(pf, vf1, O[qs][1], 0, 0, 0);
            lacc[qs] = __builtin_amdgcn_mfma_f32_16x16x32_f16(pf, onesv, lacc[qs], 0, 0, 0);
        }
        kf0 = nkf0; kf1 = nkf1; vf0 = nvf0; vf1 = nvf1;
        aa++;
    }

    // ---- merge: wave1 stores partials, wave0 adds and finishes ----
    if (w == 1) {
        float* ob = Olds[lane];
        #pragma unroll
        for (int qs = 0; qs < 4; qs++) {
            *(f32x4*)&ob[qs * 12]     = O[qs][0];
            *(f32x4*)&ob[qs * 12 + 4] = O[qs][1];
            *(f32x4*)&ob[qs * 12 + 8] = lacc[qs];
        }
    }
    __syncthreads();
    if (w == 0) {
        const float* ob = Olds[lane];
        #pragma unroll
        for (int qs = 0; qs < 4; qs++) {
            O[qs][0] += *(const f32x4*)&ob[qs * 12];
            O[qs][1] += *(const f32x4*)&ob[qs * 12 + 4];
            lacc[qs] += *(const f32x4*)&ob[qs * 12 + 8];
            #pragma unroll
            for (int r = 0; r < 4; r++) {
                float li = 1.f / lacc[qs][r];
                int ql = qs * 16 + quad * 4 + r;
                int qi = i0 + (ql >> 3), qj = j0 + (ql & 7);
                size_t base = (size_t)(qi * PP + qj) * CC + h * HD;
                ao[base + nn]      = (f16)(O[qs][0][r] * li);
                ao[base + 16 + nn] = (f16)(O[qs][1][r] * li);
            }
        }
    }
}

extern "C" void kernel_launch(void* const* d_in, const int* in_sizes, int n_in,
                              void* d_out, int out_size, void* d_ws, size_t ws_size,
                              hipStream_t stream) {
    (void)in_sizes; (void)n_in; (void)out_size; (void)ws_size;
    const float* x    = (const float*)d_in[0];
    const float* cond = (const float*)d_in[1];
    const float* mask = (const float*)d_in[2];
    const float* lw   = (const float*)d_in[3];
    const float* lb   = (const float*)d_in[4];
    const float* qw   = (const float*)d_in[5];
    const float* qb   = (const float*)d_in[6];
    const float* rpb  = (const float*)d_in[7];
    const float* pw   = (const float*)d_in[8];
    const float* pb   = (const float*)d_in[9];
    float* outp       = (float*)d_out;

    float* ws   = (float*)d_ws;
    float* qbs  = ws;                 // 384
    float* b2s  = qbs + 384;          // 384
    float* rpbp = b2s + 384;          // 10240 padded
    f16* lwh  = (f16*)(rpbp + 10240);             // 128*160
    f16* qwh  = lwh + 20480;                      // 384*128
    f16* pwh  = qwh + 49152;                      // 128*128
    f16* w2h  = pwh + 16384;                      // 384*128
    f16* yh   = w2h + 49152;                      // NN*128
    f16* qkh  = yh + (size_t)NN * 128;            // NN*256 (Q|K)
    f16* vt   = qkh + (size_t)NN * 256;           // 128*NPAD
    f16* ao   = vt + (size_t)128 * NPAD;          // NN*128  (prefetch overshoot lands in vt/ao)

    prep<<<228, 256, 0, stream>>>(lw, qw, pw, qb, pb, rpb, lwh, qwh, pwh, w2h, qbs, b2s, rpbp);
    fusion_gemm<<<dim3(352, 2), 256, 0, stream>>>(x, cond, mask, lwh, lb, yh);
    gemm_qkv<<<dim3(352, 6), 256, 0, stream>>>(yh, qwh, qbs, qkh, vt);
    attn_mfma<<<dim3(TT / 8, PP / 8, HEADS), 128, 0, stream>>>(qkh, vt, rpbp, ao);
    gemm_qkv<<<dim3(352, 6), 256, 0, stream>>>(ao, w2h, b2s, qkh, vt);   // fused proj+qkv
    attn_mfma<<<dim3(TT / 8, PP / 8, HEADS), 128, 0, stream>>>(qkh, vt, rpbp, ao);
    gemm_out<<<dim3(352, 2), 256, 0, stream>>>(ao, pwh, pb, outp);
}